// Round 5
// baseline (1196.957 us; speedup 1.0000x reference)
//
#include <hip/hip_runtime.h>
#include <hip/hip_cooperative_groups.h>
#include <stdint.h>

namespace cg = cooperative_groups;

// ---------------- problem constants ----------------
static constexpr int    N_NODES = 50000;
static constexpr int    N_EDGES = 800000;
static constexpr int    DIN     = 512;
static constexpr int    DOUT    = 128;
static constexpr size_t SEQ_ELEMS = (size_t)N_NODES * DIN;   // 25,600,000
static constexpr size_t H_ELEMS   = (size_t)N_NODES * DOUT;  //  6,400,000

// radix geometry: 49 tiles x 1024
static constexpr int RS_NB = 49;

typedef __attribute__((ext_vector_type(8))) short bf16x8;
typedef __attribute__((ext_vector_type(4))) float f32x4;
typedef __attribute__((ext_vector_type(4))) unsigned short u16x4;

// ---------------- workspace layout (u32 word offsets) ----------------
static constexpr size_t W_DEGCNT = 0;                       // 50000
static constexpr size_t W_CURSOR = W_DEGCNT + 50000;        // 50000
static constexpr size_t W_SUMBUF = W_CURSOR + 50000;        // 128 (float)
static constexpr size_t W_COUNTER= W_SUMBUF + 128;          // 8
static constexpr size_t W_BLKSUM = W_COUNTER + 8;           // 256
static constexpr size_t W_HISTA  = W_BLKSUM + 256;          // 12544
static constexpr size_t W_HISTB  = W_HISTA + 12544;         // 12544
static constexpr size_t W_OFFS   = W_HISTB + 12544;         // 12544
static constexpr size_t W_ROWPTR = W_OFFS + 12544;          // 50001
static constexpr size_t W_COLSRC = W_ROWPTR + 50004;        // 800000
static constexpr size_t W_DINV   = W_COLSRC + 800000;       // 50000 (float)
static constexpr size_t W_KA     = W_DINV + 50000;          // 50000
static constexpr size_t W_KB     = W_KA + 50000;            // 50000
static constexpr size_t W_VA     = W_KB + 50000;            // 50000 (final perm)
static constexpr size_t W_VB     = W_VA + 50000;            // 50000
static constexpr size_t W_BT     = (W_VB + 50000 + 3) & ~(size_t)3;  // 32768 (bf16 128x512), 16B aligned
static constexpr size_t W_HWPOS  = W_BT + 32768;            // 3,200,000 (bf16 6.4M)
static constexpr size_t W_HWNEG  = W_HWPOS + 3200000;       // 3,200,000

// ---------------- helpers ----------------
__device__ __forceinline__ uint16_t f2bf(float f) {
  uint32_t u = __float_as_uint(f);
  return (uint16_t)((u + 0x7FFFu + ((u >> 16) & 1u)) >> 16);
}
__device__ __forceinline__ float b2f(uint16_t h) {
  return __uint_as_float(((uint32_t)h) << 16);
}

__device__ __forceinline__ uint32_t rotl32(uint32_t x, int r) {
  return (x << r) | (x >> (32 - r));
}

__device__ __forceinline__ void threefry2x32(uint32_t k0, uint32_t k1,
                                             uint32_t x0, uint32_t x1,
                                             uint32_t& o0, uint32_t& o1) {
  uint32_t ks0 = k0, ks1 = k1, ks2 = k0 ^ k1 ^ 0x1BD11BDAu;
  x0 += ks0; x1 += ks1;
#define TF_ROUND(r) { x0 += x1; x1 = rotl32(x1, (r)); x1 ^= x0; }
  TF_ROUND(13) TF_ROUND(15) TF_ROUND(26) TF_ROUND(6)
  x0 += ks1; x1 += ks2 + 1u;
  TF_ROUND(17) TF_ROUND(29) TF_ROUND(16) TF_ROUND(24)
  x0 += ks2; x1 += ks0 + 2u;
  TF_ROUND(13) TF_ROUND(15) TF_ROUND(26) TF_ROUND(6)
  x0 += ks0; x1 += ks1 + 3u;
  TF_ROUND(17) TF_ROUND(29) TF_ROUND(16) TF_ROUND(24)
  x0 += ks1; x1 += ks2 + 4u;
  TF_ROUND(13) TF_ROUND(15) TF_ROUND(26) TF_ROUND(6)
  x0 += ks2; x1 += ks0 + 5u;
#undef TF_ROUND
  o0 = x0; o1 = x1;
}

__device__ __forceinline__ uint32_t randbits32(uint32_t k0, uint32_t k1, uint32_t ctr) {
  uint32_t a, b;
  threefry2x32(k0, k1, 0u, ctr, a, b);
  return a ^ b;
}

// ---------------- W (512x128 f32) -> BT (128x512 bf16) ----------------
__global__ void __launch_bounds__(256) wt_bf16_kernel(const float* __restrict__ W,
                                                      uint16_t* __restrict__ BT) {
  __shared__ float tile[32][129];
  int k0 = blockIdx.x * 32;
  int t = threadIdx.x;
  for (int i = t; i < 32 * 128; i += 256) {
    int k = i >> 7, n = i & 127;
    tile[k][n] = W[(size_t)(k0 + k) * DOUT + n];
  }
  __syncthreads();
  for (int i = t; i < 32 * 128; i += 256) {
    int n = i >> 5, k = i & 31;
    BT[(size_t)n * DIN + k0 + k] = f2bf(tile[k][n]);
  }
}

// ---------------- fused dropout + MFMA bf16 GEMM ----------------
__global__ void __launch_bounds__(256) dg_kernel(const float* __restrict__ x,
                                                 const uint16_t* __restrict__ BT,
                                                 const float* __restrict__ pprob,
                                                 float* __restrict__ seq_pos,
                                                 float* __restrict__ seq_neg,
                                                 uint16_t* __restrict__ hw_pos,
                                                 uint16_t* __restrict__ hw_neg, int M) {
  __shared__ __align__(16) uint16_t ldsA[64 * 64];
  __shared__ __align__(16) uint16_t ldsB[128 * 64];
  const int which = blockIdx.y;
  float*    seq = which ? seq_neg : seq_pos;
  uint16_t* hwb = which ? hw_neg : hw_pos;

  // dropout keys: split(key(1),3)[which]
  uint32_t kk0, kk1;
  threefry2x32(0u, 1u, 0u, (uint32_t)which, kk0, kk1);
  const float p = pprob[0];
  const float keep_p = 1.0f - p;
  const float scale  = 1.0f / keep_p;
  uint32_t Tint = (uint32_t)ceilf(keep_p * 8388608.0f);  // keep iff (bits>>9) < Tint
  uint32_t Tu = (Tint >= (1u << 23)) ? 0xFFFFFFFFu : (Tint << 9);

  const int tid  = threadIdx.x;
  const int lane = tid & 63;
  const int w    = tid >> 6;
  const int wr   = w >> 1, wc = w & 1;
  const int m0   = blockIdx.x * 64;
  const int l15  = lane & 15, l4 = lane >> 4;
  const int lr   = lane >> 3, lk = (lane & 7) * 8;

  f32x4 acc[2][4] = {};

  for (int k0 = 0; k0 < DIN; k0 += 64) {
    // B tile: async global->LDS
#pragma unroll
    for (int s = 0; s < 4; ++s) {
      int nbase = w * 32 + s * 8;
      const uint16_t* gp = BT + (size_t)(nbase + lr) * DIN + k0 + lk;
      __builtin_amdgcn_global_load_lds(
          (const __attribute__((address_space(1))) void*)gp,
          (__attribute__((address_space(3))) void*)(ldsB + nbase * 64), 16, 0, 0);
    }
    // A tile: load x, dropout (integer threshold), write seq f32, stage bf16 (trunc pack)
#pragma unroll
    for (int i = 0; i < 4; ++i) {
      int idx = tid + i * 256;
      int row = idx >> 4, q = idx & 15;
      int grow = m0 + row;
      bool valid = grow < M;
      int crow = valid ? grow : (M - 1);
      float4 v = *reinterpret_cast<const float4*>(x + (size_t)crow * DIN + k0 + q * 4);
      float r[4] = {v.x, v.y, v.z, v.w};
      uint32_t cbase = (uint32_t)crow * DIN + k0 + q * 4;
#pragma unroll
      for (int j = 0; j < 4; ++j) {
        uint32_t bits = randbits32(kk0, kk1, cbase + j);
        r[j] = (bits < Tu) ? r[j] * scale : 0.0f;
      }
      if (valid)
        *reinterpret_cast<float4*>(seq + (size_t)grow * DIN + k0 + q * 4) =
            make_float4(r[0], r[1], r[2], r[3]);
      uint32_t u0 = __float_as_uint(r[0]), u1 = __float_as_uint(r[1]);
      uint32_t lo = (u0 >> 16) | (u1 & 0xFFFF0000u);
      u0 = __float_as_uint(r[2]); u1 = __float_as_uint(r[3]);
      uint32_t hi = (u0 >> 16) | (u1 & 0xFFFF0000u);
      *reinterpret_cast<uint2*>(&ldsA[row * 64 + q * 4]) = make_uint2(lo, hi);
    }
    asm volatile("s_waitcnt vmcnt(0)" ::: "memory");
    __syncthreads();
#pragma unroll
    for (int kk = 0; kk < 2; ++kk) {
      bf16x8 afr[2], bfr[4];
#pragma unroll
      for (int f = 0; f < 2; ++f)
        afr[f] = *reinterpret_cast<const bf16x8*>(ldsA + (wr * 32 + f * 16 + l15) * 64 + kk * 32 + l4 * 8);
#pragma unroll
      for (int f = 0; f < 4; ++f)
        bfr[f] = *reinterpret_cast<const bf16x8*>(ldsB + (wc * 64 + f * 16 + l15) * 64 + kk * 32 + l4 * 8);
#pragma unroll
      for (int fm = 0; fm < 2; ++fm)
#pragma unroll
        for (int fn = 0; fn < 4; ++fn)
          acc[fm][fn] = __builtin_amdgcn_mfma_f32_16x16x32_bf16(afr[fm], bfr[fn], acc[fm][fn], 0, 0, 0);
    }
    __syncthreads();
  }
#pragma unroll
  for (int fm = 0; fm < 2; ++fm) {
#pragma unroll
    for (int r = 0; r < 4; ++r) {
      int row = m0 + wr * 32 + fm * 16 + l4 * 4 + r;
      if (row < M) {
        uint16_t* cp = hwb + (size_t)row * DOUT + wc * 64 + l15;
#pragma unroll
        for (int fn = 0; fn < 4; ++fn)
          cp[fn * 16] = f2bf(acc[fm][fn][r]);
      }
    }
  }
}

// ---------------- cooperative kernel: CSR build + permutation (2x radix-256 sort) ----------------
__global__ void __launch_bounds__(256) coop_kernel(const int* __restrict__ ei,
                                                   uint32_t* __restrict__ wsu) {
  cg::grid_group gridg = cg::this_grid();
  __shared__ uint32_t lds[12800];  // 50 KB multi-purpose

  uint32_t* degcnt = wsu + W_DEGCNT;
  uint32_t* cursor = wsu + W_CURSOR;
  float*    sumbuf = (float*)(wsu + W_SUMBUF);
  uint32_t* counter= wsu + W_COUNTER;
  uint32_t* blksum = wsu + W_BLKSUM;
  uint32_t* histA  = wsu + W_HISTA;
  uint32_t* histB  = wsu + W_HISTB;
  uint32_t* offs   = wsu + W_OFFS;
  uint32_t* rowptr = wsu + W_ROWPTR;
  uint32_t* colsrc = wsu + W_COLSRC;
  float*    dinv   = (float*)(wsu + W_DINV);
  uint32_t* kA     = wsu + W_KA;
  uint32_t* kB     = wsu + W_KB;
  uint32_t* vA     = wsu + W_VA;
  uint32_t* vB     = wsu + W_VB;

  const int t = threadIdx.x;
  const int b = blockIdx.x;
  const int gt = b * 256 + t;

  // shuffle subkeys (redundant per thread; cheap)
  uint32_t k3a, k3b, ra, rb, s1a, s1b, s2a, s2b;
  threefry2x32(0u, 1u, 0u, 2u, k3a, k3b);
  threefry2x32(k3a, k3b, 0u, 0u, ra, rb);
  threefry2x32(k3a, k3b, 0u, 1u, s1a, s1b);
  threefry2x32(ra, rb, 0u, 1u, s2a, s2b);

  // P0: zero accumulators
  for (int i = gt; i < N_NODES; i += 65536) { degcnt[i] = 0u; cursor[i] = 0u; }
  if (gt < 128) sumbuf[gt] = 0.0f;
  if (gt == 128) counter[0] = 0u;
  gridg.sync();

  // P1: in-degree histogram
  for (int e = gt; e < N_EDGES; e += 65536)
    atomicAdd(&degcnt[ei[N_EDGES + e]], 1u);
  gridg.sync();

  // P2: per-block scan + dinv
  {
    uint32_t v = (gt < N_NODES) ? degcnt[gt] : 0u;
    if (gt < N_NODES) dinv[gt] = 1.0f / sqrtf((float)(v + 1u));
    lds[t] = v;
    __syncthreads();
    for (int off = 1; off < 256; off <<= 1) {
      uint32_t xx = (t >= off) ? lds[t - off] : 0u;
      __syncthreads();
      lds[t] += xx;
      __syncthreads();
    }
    if (gt < N_NODES) rowptr[gt] = lds[t] - v;
    if (t == 255) blksum[b] = lds[255];
  }
  gridg.sync();

  // P3: block 0 scans blksum
  if (b == 0) {
    uint32_t v = blksum[t];
    lds[t] = v;
    __syncthreads();
    for (int off = 1; off < 256; off <<= 1) {
      uint32_t xx = (t >= off) ? lds[t - off] : 0u;
      __syncthreads();
      lds[t] += xx;
      __syncthreads();
    }
    blksum[t] = lds[t] - v;
  }
  gridg.sync();

  // P4: finalize rowptr
  if (gt < N_NODES) rowptr[gt] += blksum[b];
  if (gt == 0) rowptr[N_NODES] = (uint32_t)N_EDGES;
  gridg.sync();

  // keygen + pass-0 tile histogram (blocks 0..48)
  auto keygen = [&](uint32_t ka, uint32_t kb, bool iota) {
    if (b < RS_NB) {
      lds[t] = 0u;
      __syncthreads();
      int base = b * 1024;
#pragma unroll
      for (int i = 0; i < 4; ++i) {
        int pp = base + t + i * 256;
        if (pp < N_NODES) {
          uint32_t kv = randbits32(ka, kb, (uint32_t)pp);
          kA[pp] = kv;
          if (iota) vA[pp] = (uint32_t)pp;
          atomicAdd(&lds[kv & 255u], 1u);
        }
      }
      __syncthreads();
      histA[t * RS_NB + b] = lds[t];
    }
  };

  // P5: CSR fill + round-0 keygen
  for (int e = gt; e < N_EDGES; e += 65536) {
    int s = ei[e], d = ei[N_EDGES + e];
    uint32_t pos = rowptr[d] + atomicAdd(&cursor[d], 1u);
    colsrc[pos] = (uint32_t)s;
  }
  keygen(s1a, s1b, true);
  gridg.sync();

  // ---- 2 rounds x 4 passes of stable radix-256 ----
  for (int round = 0; round < 2; ++round) {
    if (round == 1) { keygen(s2a, s2b, false); gridg.sync(); }
    for (int pass = 0; pass < 4; ++pass) {
      const int shift = pass * 8;
      uint32_t* Hcur = (pass & 1) ? histB : histA;
      uint32_t* Hnxt = (pass & 1) ? histA : histB;
      const uint32_t* ki = (pass & 1) ? kB : kA;
      const uint32_t* vi = (pass & 1) ? vB : vA;
      uint32_t* ko = (pass & 1) ? kA : kB;
      uint32_t* vo = (pass & 1) ? vA : vB;

      // offs phase: block 0 computes stable global offsets; others zero next hist
      if (b == 0) {
        for (int i = t; i < 256 * RS_NB; i += 256) lds[i] = Hcur[i];
        __syncthreads();
        uint32_t sum = 0;
        for (int j = 0; j < RS_NB; ++j) sum += lds[t * RS_NB + j];
        lds[12544 + t] = sum;
        __syncthreads();
        for (int off = 1; off < 256; off <<= 1) {
          uint32_t xx = (t >= off) ? lds[12544 + t - off] : 0u;
          __syncthreads();
          lds[12544 + t] += xx;
          __syncthreads();
        }
        uint32_t run = lds[12544 + t] - sum;  // exclusive digit base
        for (int j = 0; j < RS_NB; ++j) {
          uint32_t h = lds[t * RS_NB + j];
          offs[t * RS_NB + j] = run;
          run += h;
        }
      } else if (pass < 3) {
        for (int i = (b - 1) * 256 + t; i < 256 * RS_NB; i += 255 * 256) Hnxt[i] = 0u;
      }
      gridg.sync();

      // scatter phase: blocks 0..48, ballot-based stable ranking
      if (b < RS_NB) {
        for (int i = t; i < 4096; i += 256) lds[i] = 0u;  // ghist[16][256]
        __syncthreads();
        const int w = t >> 6, l = t & 63;
        const uint64_t pre = (1ull << l) - 1ull;
        uint32_t myk[4], myd[4];
        int myr[4];
        bool myv[4];
        int base = b * 1024;
#pragma unroll
        for (int j = 0; j < 4; ++j) {
          int idx = w * 256 + j * 64 + l;  // element index within tile (group g=4w+j)
          int pp = base + idx;
          bool valid = pp < N_NODES;
          uint32_t kv = valid ? ki[pp] : 0u;
          uint32_t d = (kv >> shift) & 255u;
          uint64_t m = __ballot(valid);
#pragma unroll
          for (int bit = 0; bit < 8; ++bit) {
            uint64_t bb = __ballot((d >> bit) & 1u);
            m &= ((d >> bit) & 1u) ? bb : ~bb;
          }
          int peer = __popcll(m & pre);
          if (valid && peer == 0) lds[(w * 4 + j) * 256 + d] = (uint32_t)__popcll(m);
          myk[j] = kv; myd[j] = d; myr[j] = peer; myv[j] = valid;
        }
        __syncthreads();
        {  // group prefix per digit (thread t = digit t)
          uint32_t run = 0;
#pragma unroll
          for (int g = 0; g < 16; ++g) {
            uint32_t tmp = lds[g * 256 + t];
            lds[g * 256 + t] = run;
            run += tmp;
          }
        }
        __syncthreads();
#pragma unroll
        for (int j = 0; j < 4; ++j) {
          if (myv[j]) {
            int idx = w * 256 + j * 64 + l;
            int pp = base + idx;
            uint32_t pos = offs[myd[j] * RS_NB + b] + lds[(w * 4 + j) * 256 + myd[j]] + (uint32_t)myr[j];
            ko[pos] = myk[j];
            vo[pos] = vi[pp];
            if (pass < 3)
              atomicAdd(&Hnxt[((myk[j] >> (shift + 8)) & 255u) * RS_NB + (pos >> 10)], 1u);
          }
        }
      }
      gridg.sync();
    }
  }
  // result: perm in vA
}

// ---------------- GCN gather conv (bf16 hw, float4 cols per lane, 8 nodes/block) ----------------
__global__ void __launch_bounds__(256) gcn_gather_kernel(const uint16_t* __restrict__ hw_pos,
                                                         const uint16_t* __restrict__ hw_neg,
                                                         const float* __restrict__ dinv,
                                                         const uint32_t* __restrict__ rowptr,
                                                         const uint32_t* __restrict__ colsrc,
                                                         const uint32_t* __restrict__ perm,
                                                         const float* __restrict__ bias,
                                                         float* __restrict__ out_pos,
                                                         float* __restrict__ out_neg) {
  const bool use_perm = blockIdx.y != 0;
  const uint16_t* hw = use_perm ? hw_neg : hw_pos;
  float* outh = use_perm ? out_neg : out_pos;
  int node = blockIdx.x * 8 + (threadIdx.x >> 5);
  if (node >= N_NODES) return;
  int c4 = (threadIdx.x & 31) * 4;
  uint32_t e0 = rowptr[node], e1 = rowptr[node + 1];
  float ax = 0.f, ay = 0.f, az = 0.f, aw = 0.f;
  for (uint32_t e = e0; e < e1; ++e) {
    uint32_t s = colsrc[e];
    float dv = dinv[s];
    uint32_t srow = use_perm ? perm[s] : s;
    u16x4 v = *reinterpret_cast<const u16x4*>(hw + (size_t)srow * DOUT + c4);
    ax += b2f(v.x) * dv; ay += b2f(v.y) * dv; az += b2f(v.z) * dv; aw += b2f(v.w) * dv;
  }
  float dn = dinv[node];
  uint32_t nrow = use_perm ? perm[node] : (uint32_t)node;
  u16x4 sv = *reinterpret_cast<const u16x4*>(hw + (size_t)nrow * DOUT + c4);
  float4 bv = *reinterpret_cast<const float4*>(bias + c4);
  float d2 = dn * dn;
  float4 o;
  o.x = fmaxf(dn * ax + d2 * b2f(sv.x) + bv.x, 0.0f);
  o.y = fmaxf(dn * ay + d2 * b2f(sv.y) + bv.y, 0.0f);
  o.z = fmaxf(dn * az + d2 * b2f(sv.z) + bv.z, 0.0f);
  o.w = fmaxf(dn * aw + d2 * b2f(sv.w) + bv.w, 0.0f);
  *reinterpret_cast<float4*>(outh + (size_t)node * DOUT + c4) = o;
}

// ---------------- summary: colsum + last-block sigmoid ----------------
__global__ void __launch_bounds__(128) colsum_sig_kernel(const float* __restrict__ ph,
                                                         float* __restrict__ sumbuf,
                                                         uint32_t* __restrict__ counter,
                                                         float* __restrict__ outs) {
  int c = threadIdx.x;  // 0..127
  int r0 = blockIdx.x * 256;
  int r1 = r0 + 256; if (r1 > N_NODES) r1 = N_NODES;
  float s = 0.0f;
  for (int r = r0; r < r1; ++r) s += ph[(size_t)r * DOUT + c];
  atomicAdd(&sumbuf[c], s);
  __threadfence();
  __syncthreads();
  __shared__ uint32_t lastflag;
  if (c == 0) lastflag = atomicAdd(counter, 1u);
  __syncthreads();
  if (lastflag == gridDim.x - 1) {
    __threadfence();
    float m = atomicAdd(&sumbuf[c], 0.0f) * (1.0f / (float)N_NODES);  // coherent read
    outs[c] = 1.0f / (1.0f + expf(-m));
  }
}

// ---------------- launch ----------------
extern "C" void kernel_launch(void* const* d_in, const int* in_sizes, int n_in,
                              void* d_out, int out_size, void* d_ws, size_t ws_size,
                              hipStream_t stream) {
  const float* x     = (const float*)d_in[0];
  const int*   ei    = (const int*)d_in[1];
  const float* W     = (const float*)d_in[2];
  const float* bias  = (const float*)d_in[3];
  const float* pprob = (const float*)d_in[4];

  float* out = (float*)d_out;
  float* out_pos_h   = out;
  float* out_neg_h   = out + H_ELEMS;
  float* out_summary = out + 2 * H_ELEMS;
  float* out_pos_seq = out + 2 * H_ELEMS + DOUT;
  float* out_neg_seq = out_pos_seq + SEQ_ELEMS;

  uint32_t* wsu = (uint32_t*)d_ws;
  float*    sumbuf = (float*)(wsu + W_SUMBUF);
  uint32_t* counter= wsu + W_COUNTER;
  uint32_t* rowptr = wsu + W_ROWPTR;
  uint32_t* colsrc = wsu + W_COLSRC;
  float*    dinv   = (float*)(wsu + W_DINV);
  uint32_t* permv  = wsu + W_VA;
  uint16_t* BT     = (uint16_t*)(wsu + W_BT);
  uint16_t* hw_pos = (uint16_t*)(wsu + W_HWPOS);
  uint16_t* hw_neg = (uint16_t*)(wsu + W_HWNEG);

  // 1) W -> bf16 transposed
  wt_bf16_kernel<<<DIN / 32, 256, 0, stream>>>(W, BT);

  // 2) fused dropout + GEMM (both branches)
  dim3 dgrid((N_NODES + 63) / 64, 2);
  dg_kernel<<<dgrid, 256, 0, stream>>>(x, BT, pprob, out_pos_seq, out_neg_seq,
                                       hw_pos, hw_neg, N_NODES);

  // 3) cooperative: CSR + permutation
  {
    const int* ei_arg = ei;
    uint32_t* ws_arg = wsu;
    void* cargs[] = {(void*)&ei_arg, (void*)&ws_arg};
    hipLaunchCooperativeKernel((void*)coop_kernel, dim3(256), dim3(256), cargs, 0, stream);
  }

  // 4) gather convs (both branches)
  dim3 ggrid2((N_NODES + 7) / 8, 2);
  gcn_gather_kernel<<<ggrid2, 256, 0, stream>>>(hw_pos, hw_neg, dinv, rowptr, colsrc,
                                                permv, bias, out_pos_h, out_neg_h);

  // 5) summary
  colsum_sig_kernel<<<(N_NODES + 255) / 256, 128, 0, stream>>>(out_pos_h, sumbuf,
                                                               counter, out_summary);

  (void)in_sizes; (void)n_in; (void)out_size; (void)ws_size;
}

// Round 6
// 734.401 us; speedup vs baseline: 1.6298x; 1.6298x over previous
//
#include <hip/hip_runtime.h>
#include <stdint.h>

// ---------------- problem constants ----------------
static constexpr int    N_NODES = 50000;
static constexpr int    N_EDGES = 800000;
static constexpr int    DIN     = 512;
static constexpr int    DOUT    = 128;
static constexpr size_t SEQ_ELEMS = (size_t)N_NODES * DIN;   // 25,600,000
static constexpr size_t H_ELEMS   = (size_t)N_NODES * DOUT;  //  6,400,000

// radix geometry: 49 tiles x 1024
static constexpr int RS_NB = 49;

typedef __attribute__((ext_vector_type(8))) short bf16x8;
typedef __attribute__((ext_vector_type(4))) float f32x4;
typedef __attribute__((ext_vector_type(4))) unsigned short u16x4;

// ---------------- workspace layout (u32 word offsets) ----------------
static constexpr size_t W_HDR    = 0;                     // 16
static constexpr size_t W_DEGCNT = 16;                    // 50000
static constexpr size_t W_CURSOR = W_DEGCNT + 50000;      // 50000  (=50016)
static constexpr size_t W_SUMBUF = W_CURSOR + 50000;      // 128    (=100016)
static constexpr size_t W_COUNTER= W_SUMBUF + 128;        // 8      (=100144)
static constexpr size_t W_ZEND   = W_COUNTER + 8;         // zero range end (=100152)
static constexpr size_t W_HISTA  = W_ZEND;                // 12544
static constexpr size_t W_HISTB  = W_HISTA + 12544;       // 12544
static constexpr size_t W_OFFS   = W_HISTB + 12544;       // 12544
static constexpr size_t W_ROWPTR = W_OFFS + 12544;        // 50001 (+pad)
static constexpr size_t W_COLSRC = W_ROWPTR + 50004;      // 800000
static constexpr size_t W_DINV   = W_COLSRC + 800000;     // 50000 (float)
static constexpr size_t W_KA     = W_DINV + 50000;        // 50000
static constexpr size_t W_KB     = W_KA + 50000;          // 50000
static constexpr size_t W_VA     = W_KB + 50000;          // 50000 (final perm)
static constexpr size_t W_VB     = W_VA + 50000;          // 50000
static constexpr size_t W_BT     = W_VB + 50000;          // 32768 (bf16 128x512) — byte 4951152, 16B aligned
static constexpr size_t W_HWPOS  = W_BT + 32768;          // 3,200,000 (bf16)
static constexpr size_t W_HWNEG  = W_HWPOS + 3200000;     // 3,200,000

// ---------------- helpers ----------------
__device__ __forceinline__ uint16_t f2bf(float f) {
  uint32_t u = __float_as_uint(f);
  return (uint16_t)((u + 0x7FFFu + ((u >> 16) & 1u)) >> 16);
}
__device__ __forceinline__ float b2f(uint16_t h) {
  return __uint_as_float(((uint32_t)h) << 16);
}

__device__ __forceinline__ uint32_t rotl32(uint32_t x, int r) {
  return (x << r) | (x >> (32 - r));
}

__device__ __forceinline__ void threefry2x32(uint32_t k0, uint32_t k1,
                                             uint32_t x0, uint32_t x1,
                                             uint32_t& o0, uint32_t& o1) {
  uint32_t ks0 = k0, ks1 = k1, ks2 = k0 ^ k1 ^ 0x1BD11BDAu;
  x0 += ks0; x1 += ks1;
#define TF_ROUND(r) { x0 += x1; x1 = rotl32(x1, (r)); x1 ^= x0; }
  TF_ROUND(13) TF_ROUND(15) TF_ROUND(26) TF_ROUND(6)
  x0 += ks1; x1 += ks2 + 1u;
  TF_ROUND(17) TF_ROUND(29) TF_ROUND(16) TF_ROUND(24)
  x0 += ks2; x1 += ks0 + 2u;
  TF_ROUND(13) TF_ROUND(15) TF_ROUND(26) TF_ROUND(6)
  x0 += ks0; x1 += ks1 + 3u;
  TF_ROUND(17) TF_ROUND(29) TF_ROUND(16) TF_ROUND(24)
  x0 += ks1; x1 += ks2 + 4u;
  TF_ROUND(13) TF_ROUND(15) TF_ROUND(26) TF_ROUND(6)
  x0 += ks2; x1 += ks0 + 5u;
#undef TF_ROUND
  o0 = x0; o1 = x1;
}

__device__ __forceinline__ uint32_t randbits32(uint32_t k0, uint32_t k1, uint32_t ctr) {
  uint32_t a, b;
  threefry2x32(k0, k1, 0u, ctr, a, b);
  return a ^ b;
}

// ---------------- init: zero accumulators + shuffle keys + W->BT transpose ----------------
__global__ void __launch_bounds__(256) wt_init_kernel(const float* __restrict__ W,
                                                      uint16_t* __restrict__ BT,
                                                      uint32_t* __restrict__ wsu) {
  // zero degcnt/cursor/sumbuf/counter
  {
    int gid = blockIdx.x * 256 + threadIdx.x;  // 16*256 = 4096 threads
    for (size_t i = W_DEGCNT + gid; i < W_ZEND; i += 4096) wsu[i] = 0u;
  }
  // shuffle subkeys -> hdr
  if (blockIdx.x == 0 && threadIdx.x == 0) {
    uint32_t k3a, k3b, ra, rb, s1a, s1b, s2a, s2b;
    threefry2x32(0u, 1u, 0u, 2u, k3a, k3b);   // split(key(1),3)[2]
    threefry2x32(k3a, k3b, 0u, 0u, ra, rb);   // round1 carry key
    threefry2x32(k3a, k3b, 0u, 1u, s1a, s1b); // round1 subkey
    threefry2x32(ra, rb, 0u, 1u, s2a, s2b);   // round2 subkey
    wsu[4] = s1a; wsu[5] = s1b; wsu[6] = s2a; wsu[7] = s2b;
  }
  // W (512x128 f32) -> BT (128x512 bf16)
  __shared__ float tile[32][129];
  int k0 = blockIdx.x * 32;
  int t = threadIdx.x;
  for (int i = t; i < 32 * 128; i += 256) {
    int k = i >> 7, n = i & 127;
    tile[k][n] = W[(size_t)(k0 + k) * DOUT + n];
  }
  __syncthreads();
  for (int i = t; i < 32 * 128; i += 256) {
    int n = i >> 5, k = i & 31;
    BT[(size_t)n * DIN + k0 + k] = f2bf(tile[k][n]);
  }
}

// ---------------- fused dropout + MFMA bf16 GEMM ----------------
__global__ void __launch_bounds__(256) dg_kernel(const float* __restrict__ x,
                                                 const uint16_t* __restrict__ BT,
                                                 const float* __restrict__ pprob,
                                                 float* __restrict__ seq_pos,
                                                 float* __restrict__ seq_neg,
                                                 uint16_t* __restrict__ hw_pos,
                                                 uint16_t* __restrict__ hw_neg, int M) {
  __shared__ __align__(16) uint16_t ldsA[64 * 64];
  __shared__ __align__(16) uint16_t ldsB[128 * 64];
  const int which = blockIdx.y;
  float*    seq = which ? seq_neg : seq_pos;
  uint16_t* hwb = which ? hw_neg : hw_pos;

  uint32_t kk0, kk1;
  threefry2x32(0u, 1u, 0u, (uint32_t)which, kk0, kk1);  // split(key(1),3)[which]
  const float p = pprob[0];
  const float keep_p = 1.0f - p;
  const float scale  = 1.0f / keep_p;
  uint32_t Tint = (uint32_t)ceilf(keep_p * 8388608.0f);
  uint32_t Tu = (Tint >= (1u << 23)) ? 0xFFFFFFFFu : (Tint << 9);

  const int tid  = threadIdx.x;
  const int lane = tid & 63;
  const int w    = tid >> 6;
  const int wr   = w >> 1, wc = w & 1;
  const int m0   = blockIdx.x * 64;
  const int l15  = lane & 15, l4 = lane >> 4;
  const int lr   = lane >> 3, lk = (lane & 7) * 8;

  f32x4 acc[2][4] = {};

  for (int k0 = 0; k0 < DIN; k0 += 64) {
#pragma unroll
    for (int s = 0; s < 4; ++s) {
      int nbase = w * 32 + s * 8;
      const uint16_t* gp = BT + (size_t)(nbase + lr) * DIN + k0 + lk;
      __builtin_amdgcn_global_load_lds(
          (const __attribute__((address_space(1))) void*)gp,
          (__attribute__((address_space(3))) void*)(ldsB + nbase * 64), 16, 0, 0);
    }
#pragma unroll
    for (int i = 0; i < 4; ++i) {
      int idx = tid + i * 256;
      int row = idx >> 4, q = idx & 15;
      int grow = m0 + row;
      bool valid = grow < M;
      int crow = valid ? grow : (M - 1);
      float4 v = *reinterpret_cast<const float4*>(x + (size_t)crow * DIN + k0 + q * 4);
      float r[4] = {v.x, v.y, v.z, v.w};
      uint32_t cbase = (uint32_t)crow * DIN + k0 + q * 4;
#pragma unroll
      for (int j = 0; j < 4; ++j) {
        uint32_t bits = randbits32(kk0, kk1, cbase + j);
        r[j] = (bits < Tu) ? r[j] * scale : 0.0f;
      }
      if (valid)
        *reinterpret_cast<float4*>(seq + (size_t)grow * DIN + k0 + q * 4) =
            make_float4(r[0], r[1], r[2], r[3]);
      uint32_t u0 = __float_as_uint(r[0]), u1 = __float_as_uint(r[1]);
      uint32_t lo = (u0 >> 16) | (u1 & 0xFFFF0000u);
      u0 = __float_as_uint(r[2]); u1 = __float_as_uint(r[3]);
      uint32_t hi = (u0 >> 16) | (u1 & 0xFFFF0000u);
      *reinterpret_cast<uint2*>(&ldsA[row * 64 + q * 4]) = make_uint2(lo, hi);
    }
    asm volatile("s_waitcnt vmcnt(0)" ::: "memory");
    __syncthreads();
#pragma unroll
    for (int kk = 0; kk < 2; ++kk) {
      bf16x8 afr[2], bfr[4];
#pragma unroll
      for (int f = 0; f < 2; ++f)
        afr[f] = *reinterpret_cast<const bf16x8*>(ldsA + (wr * 32 + f * 16 + l15) * 64 + kk * 32 + l4 * 8);
#pragma unroll
      for (int f = 0; f < 4; ++f)
        bfr[f] = *reinterpret_cast<const bf16x8*>(ldsB + (wc * 64 + f * 16 + l15) * 64 + kk * 32 + l4 * 8);
#pragma unroll
      for (int fm = 0; fm < 2; ++fm)
#pragma unroll
        for (int fn = 0; fn < 4; ++fn)
          acc[fm][fn] = __builtin_amdgcn_mfma_f32_16x16x32_bf16(afr[fm], bfr[fn], acc[fm][fn], 0, 0, 0);
    }
    __syncthreads();
  }
#pragma unroll
  for (int fm = 0; fm < 2; ++fm) {
#pragma unroll
    for (int r = 0; r < 4; ++r) {
      int row = m0 + wr * 32 + fm * 16 + l4 * 4 + r;
      if (row < M) {
        uint16_t* cp = hwb + (size_t)row * DOUT + wc * 64 + l15;
#pragma unroll
        for (int fn = 0; fn < 4; ++fn)
          cp[fn * 16] = f2bf(acc[fm][fn][r]);
      }
    }
  }
}

// ---------------- CSR ----------------
__global__ void deg_count_kernel(const int* __restrict__ ei, uint32_t* __restrict__ degcnt) {
  int e = blockIdx.x * blockDim.x + threadIdx.x;
  if (e >= N_EDGES) return;
  atomicAdd(&degcnt[ei[N_EDGES + e]], 1u);
}

// single 1024-thread block: exclusive scan of degcnt -> rowptr, plus dinv
__global__ void __launch_bounds__(1024) csr_scan_kernel(const uint32_t* __restrict__ cnt,
                                                        uint32_t* __restrict__ rowptr,
                                                        float* __restrict__ dinv) {
  __shared__ uint32_t s[1024];
  const int t = threadIdx.x;
  int c0 = t * 49, c1 = c0 + 49;
  if (c0 > N_NODES) c0 = N_NODES;
  if (c1 > N_NODES) c1 = N_NODES;
  uint32_t sum = 0;
  for (int c = c0; c < c1; ++c) {
    uint32_t v = cnt[c];
    dinv[c] = __frsqrt_rn((float)(v + 1u));
    sum += v;
  }
  s[t] = sum;
  __syncthreads();
  for (int off = 1; off < 1024; off <<= 1) {
    uint32_t xx = (t >= off) ? s[t - off] : 0u;
    __syncthreads();
    s[t] += xx;
    __syncthreads();
  }
  uint32_t run = s[t] - sum;
  for (int c = c0; c < c1; ++c) {
    uint32_t h = cnt[c];
    rowptr[c] = run;
    run += h;
  }
  if (t == 0) rowptr[N_NODES] = (uint32_t)N_EDGES;
}

__global__ void fill_kernel(const int* __restrict__ ei, const uint32_t* __restrict__ rowptr,
                            uint32_t* __restrict__ cursor, uint32_t* __restrict__ colsrc) {
  int e = blockIdx.x * blockDim.x + threadIdx.x;
  if (e >= N_EDGES) return;
  int s = ei[e];
  int d = ei[N_EDGES + e];
  uint32_t pos = rowptr[d] + atomicAdd(&cursor[d], 1u);
  colsrc[pos] = (uint32_t)s;
}

// ---------------- radix: fused keygen + pass-0 histogram ----------------
template <bool WRITE_IOTA>
__global__ void __launch_bounds__(256) permhist_kernel(const uint32_t* __restrict__ hdr,
                                                       int keyoff,
                                                       uint32_t* __restrict__ keys,
                                                       uint32_t* __restrict__ iota,
                                                       uint32_t* __restrict__ hist, int n) {
  __shared__ uint32_t h[256];
  int t = threadIdx.x;
  h[t] = 0;
  __syncthreads();
  uint32_t k0 = hdr[keyoff], k1 = hdr[keyoff + 1];
  int base = blockIdx.x * 1024;
#pragma unroll
  for (int i = 0; i < 4; ++i) {
    int p = base + t + i * 256;
    if (p < n) {
      uint32_t kv = randbits32(k0, k1, (uint32_t)p);
      keys[p] = kv;
      if (WRITE_IOTA) iota[p] = (uint32_t)p;
      atomicAdd(&h[kv & 255u], 1u);
    }
  }
  __syncthreads();
  hist[t * gridDim.x + blockIdx.x] = h[t];
}

// wide scan: 1024 threads over 12544 digit-major cells; zero next hist
__global__ void __launch_bounds__(1024) rs_scan_kernel(const uint32_t* __restrict__ hist,
                                                       uint32_t* __restrict__ offs,
                                                       uint32_t* __restrict__ histN) {
  __shared__ uint32_t s[1024];
  const int C = 256 * RS_NB;  // 12544
  const int t = threadIdx.x;
  int c0 = t * 13, c1 = c0 + 13;
  if (c0 > C) c0 = C;
  if (c1 > C) c1 = C;
  uint32_t sum = 0;
  for (int c = c0; c < c1; ++c) sum += hist[c];
  s[t] = sum;
  __syncthreads();
  for (int off = 1; off < 1024; off <<= 1) {
    uint32_t xx = (t >= off) ? s[t - off] : 0u;
    __syncthreads();
    s[t] += xx;
    __syncthreads();
  }
  uint32_t run = s[t] - sum;
  for (int c = c0; c < c1; ++c) {
    uint32_t h = hist[c];
    offs[c] = run;
    run += h;
  }
  if (histN != nullptr)
    for (int i = t; i < C; i += 1024) histN[i] = 0u;
}

// stable scatter with ballot-based ranking (R5-verified logic)
template <bool ACC_NEXT>
__global__ void __launch_bounds__(256) rs_scatter_kernel(const uint32_t* __restrict__ ki,
                                                         const uint32_t* __restrict__ vi,
                                                         const uint32_t* __restrict__ offs,
                                                         uint32_t* __restrict__ ko,
                                                         uint32_t* __restrict__ vo,
                                                         uint32_t* __restrict__ histN,
                                                         int n, int shift) {
  __shared__ uint32_t gh[16 * 256];
  const int t = threadIdx.x;
  const int b = blockIdx.x;
  const int w = t >> 6, l = t & 63;
  const uint64_t pre = (1ull << l) - 1ull;
  for (int i = t; i < 4096; i += 256) gh[i] = 0u;
  __syncthreads();
  const int base = b * 1024;
  uint32_t myk[4], myd[4];
  int myr[4];
  bool myv[4];
#pragma unroll
  for (int j = 0; j < 4; ++j) {
    int idx = w * 256 + j * 64 + l;  // group g = 4w+j covers [64g, 64g+64)
    int pp = base + idx;
    bool valid = pp < n;
    uint32_t kv = valid ? ki[pp] : 0u;
    uint32_t d = (kv >> shift) & 255u;
    uint64_t m = __ballot(valid);
#pragma unroll
    for (int bit = 0; bit < 8; ++bit) {
      uint64_t bb = __ballot((d >> bit) & 1u);
      m &= ((d >> bit) & 1u) ? bb : ~bb;
    }
    int peer = __popcll(m & pre);
    if (valid && peer == 0) gh[(w * 4 + j) * 256 + d] = (uint32_t)__popcll(m);
    myk[j] = kv; myd[j] = d; myr[j] = peer; myv[j] = valid;
  }
  __syncthreads();
  {  // per-digit exclusive prefix over the 16 groups (thread t = digit t)
    uint32_t run = 0;
#pragma unroll
    for (int g = 0; g < 16; ++g) {
      uint32_t tmp = gh[g * 256 + t];
      gh[g * 256 + t] = run;
      run += tmp;
    }
  }
  __syncthreads();
#pragma unroll
  for (int j = 0; j < 4; ++j) {
    if (myv[j]) {
      int idx = w * 256 + j * 64 + l;
      int pp = base + idx;
      uint32_t pos = offs[myd[j] * RS_NB + b] + gh[(w * 4 + j) * 256 + myd[j]] + (uint32_t)myr[j];
      ko[pos] = myk[j];
      vo[pos] = vi[pp];
      if (ACC_NEXT)
        atomicAdd(&histN[((myk[j] >> (shift + 8)) & 255u) * RS_NB + (pos >> 10)], 1u);
    }
  }
}

// ---------------- GCN gather conv (bf16 hw, float4 cols per lane, 8 nodes/block) ----------------
__global__ void __launch_bounds__(256) gcn_gather_kernel(const uint16_t* __restrict__ hw_pos,
                                                         const uint16_t* __restrict__ hw_neg,
                                                         const float* __restrict__ dinv,
                                                         const uint32_t* __restrict__ rowptr,
                                                         const uint32_t* __restrict__ colsrc,
                                                         const uint32_t* __restrict__ perm,
                                                         const float* __restrict__ bias,
                                                         float* __restrict__ out_pos,
                                                         float* __restrict__ out_neg) {
  const bool use_perm = blockIdx.y != 0;
  const uint16_t* hw = use_perm ? hw_neg : hw_pos;
  float* outh = use_perm ? out_neg : out_pos;
  int node = blockIdx.x * 8 + (threadIdx.x >> 5);
  if (node >= N_NODES) return;
  int c4 = (threadIdx.x & 31) * 4;
  uint32_t e0 = rowptr[node], e1 = rowptr[node + 1];
  float ax = 0.f, ay = 0.f, az = 0.f, aw = 0.f;
  for (uint32_t e = e0; e < e1; ++e) {
    uint32_t s = colsrc[e];
    float dv = dinv[s];
    uint32_t srow = use_perm ? perm[s] : s;
    u16x4 v = *reinterpret_cast<const u16x4*>(hw + (size_t)srow * DOUT + c4);
    ax += b2f(v.x) * dv; ay += b2f(v.y) * dv; az += b2f(v.z) * dv; aw += b2f(v.w) * dv;
  }
  float dn = dinv[node];
  uint32_t nrow = use_perm ? perm[node] : (uint32_t)node;
  u16x4 sv = *reinterpret_cast<const u16x4*>(hw + (size_t)nrow * DOUT + c4);
  float4 bv = *reinterpret_cast<const float4*>(bias + c4);
  float d2 = dn * dn;
  float4 o;
  o.x = fmaxf(dn * ax + d2 * b2f(sv.x) + bv.x, 0.0f);
  o.y = fmaxf(dn * ay + d2 * b2f(sv.y) + bv.y, 0.0f);
  o.z = fmaxf(dn * az + d2 * b2f(sv.z) + bv.z, 0.0f);
  o.w = fmaxf(dn * aw + d2 * b2f(sv.w) + bv.w, 0.0f);
  *reinterpret_cast<float4*>(outh + (size_t)node * DOUT + c4) = o;
}

// ---------------- summary: colsum + last-block sigmoid ----------------
__global__ void __launch_bounds__(128) colsum_sig_kernel(const float* __restrict__ ph,
                                                         float* __restrict__ sumbuf,
                                                         uint32_t* __restrict__ counter,
                                                         float* __restrict__ outs) {
  int c = threadIdx.x;  // 0..127
  int r0 = blockIdx.x * 256;
  int r1 = r0 + 256; if (r1 > N_NODES) r1 = N_NODES;
  float s = 0.0f;
  for (int r = r0; r < r1; ++r) s += ph[(size_t)r * DOUT + c];
  atomicAdd(&sumbuf[c], s);
  __threadfence();
  __syncthreads();
  __shared__ uint32_t lastflag;
  if (c == 0) lastflag = atomicAdd(counter, 1u);
  __syncthreads();
  if (lastflag == gridDim.x - 1) {
    __threadfence();
    float m = atomicAdd(&sumbuf[c], 0.0f) * (1.0f / (float)N_NODES);
    outs[c] = 1.0f / (1.0f + expf(-m));
  }
}

// ---------------- launch ----------------
extern "C" void kernel_launch(void* const* d_in, const int* in_sizes, int n_in,
                              void* d_out, int out_size, void* d_ws, size_t ws_size,
                              hipStream_t stream) {
  const float* x     = (const float*)d_in[0];
  const int*   ei    = (const int*)d_in[1];
  const float* W     = (const float*)d_in[2];
  const float* bias  = (const float*)d_in[3];
  const float* pprob = (const float*)d_in[4];

  float* out = (float*)d_out;
  float* out_pos_h   = out;
  float* out_neg_h   = out + H_ELEMS;
  float* out_summary = out + 2 * H_ELEMS;
  float* out_pos_seq = out + 2 * H_ELEMS + DOUT;
  float* out_neg_seq = out_pos_seq + SEQ_ELEMS;

  uint32_t* wsu     = (uint32_t*)d_ws;
  uint32_t* hdr     = wsu + W_HDR;
  uint32_t* degcnt  = wsu + W_DEGCNT;
  uint32_t* cursor  = wsu + W_CURSOR;
  float*    sumbuf  = (float*)(wsu + W_SUMBUF);
  uint32_t* counter = wsu + W_COUNTER;
  uint32_t* histA   = wsu + W_HISTA;
  uint32_t* histB   = wsu + W_HISTB;
  uint32_t* offs    = wsu + W_OFFS;
  uint32_t* rowptr  = wsu + W_ROWPTR;
  uint32_t* colsrc  = wsu + W_COLSRC;
  float*    dinv    = (float*)(wsu + W_DINV);
  uint32_t* kA      = wsu + W_KA;
  uint32_t* kB      = wsu + W_KB;
  uint32_t* vA      = wsu + W_VA;
  uint32_t* vB      = wsu + W_VB;
  uint16_t* BT      = (uint16_t*)(wsu + W_BT);
  uint16_t* hw_pos  = (uint16_t*)(wsu + W_HWPOS);
  uint16_t* hw_neg  = (uint16_t*)(wsu + W_HWNEG);

  // 1) init (zero + keys + W transpose)
  wt_init_kernel<<<DIN / 32, 256, 0, stream>>>(W, BT, wsu);

  // 2) fused dropout + GEMM (both branches)
  dim3 dgrid((N_NODES + 63) / 64, 2);
  dg_kernel<<<dgrid, 256, 0, stream>>>(x, BT, pprob, out_pos_seq, out_neg_seq,
                                       hw_pos, hw_neg, N_NODES);

  // 3) CSR build
  deg_count_kernel<<<(N_EDGES + 255) / 256, 256, 0, stream>>>(ei, degcnt);
  csr_scan_kernel<<<1, 1024, 0, stream>>>(degcnt, rowptr, dinv);
  fill_kernel<<<(N_EDGES + 255) / 256, 256, 0, stream>>>(ei, rowptr, cursor, colsrc);

  // 4) permutation: 2 rounds x 4-pass stable radix-256
  uint32_t* H[2] = {histA, histB};
  for (int round = 0; round < 2; ++round) {
    if (round == 0)
      permhist_kernel<true><<<RS_NB, 256, 0, stream>>>(hdr, 4, kA, vA, histA, N_NODES);
    else
      permhist_kernel<false><<<RS_NB, 256, 0, stream>>>(hdr, 6, kA, nullptr, histA, N_NODES);
    for (int pass = 0; pass < 4; ++pass) {
      int shift = pass * 8;
      const uint32_t* ki = (pass & 1) ? kB : kA;
      const uint32_t* vi = (pass & 1) ? vB : vA;
      uint32_t* ko = (pass & 1) ? kA : kB;
      uint32_t* vo = (pass & 1) ? vA : vB;
      rs_scan_kernel<<<1, 1024, 0, stream>>>(H[pass & 1], offs,
                                             (pass < 3) ? H[(pass + 1) & 1] : nullptr);
      if (pass < 3)
        rs_scatter_kernel<true><<<RS_NB, 256, 0, stream>>>(
            ki, vi, offs, ko, vo, H[(pass + 1) & 1], N_NODES, shift);
      else
        rs_scatter_kernel<false><<<RS_NB, 256, 0, stream>>>(
            ki, vi, offs, ko, vo, nullptr, N_NODES, shift);
    }
  }
  const uint32_t* permv = vA;

  // 5) gather convs (both branches)
  dim3 ggrid2((N_NODES + 7) / 8, 2);
  gcn_gather_kernel<<<ggrid2, 256, 0, stream>>>(hw_pos, hw_neg, dinv, rowptr, colsrc,
                                                permv, bias, out_pos_h, out_neg_h);

  // 6) summary
  colsum_sig_kernel<<<(N_NODES + 255) / 256, 128, 0, stream>>>(out_pos_h, sumbuf,
                                                               counter, out_summary);

  (void)in_sizes; (void)n_in; (void)out_size; (void)ws_size;
}